// Round 2
// baseline (753.461 us; speedup 1.0000x reference)
//
#include <hip/hip_runtime.h>
#include <stdint.h>

#define N_NODES 100000
#define F_DIM   500
#define C_DIM   40
#define H_DIM   256
#define HX_DIM  64
#define O_DIM   320   // H + HX
#define E_NUM   1600000

typedef unsigned short u16;
typedef unsigned int   u32;
typedef __attribute__((ext_vector_type(4))) u16    u16x4;
typedef __attribute__((ext_vector_type(8))) u16    u16x8;
typedef __attribute__((ext_vector_type(4))) float  f32x4;
typedef __attribute__((ext_vector_type(8))) short  bf16x8;  // MFMA A/B frag

__device__ __forceinline__ float bf2f(u16 v) {
  u32 u = ((u32)v) << 16;
  return __builtin_bit_cast(float, u);
}
__device__ __forceinline__ u16 f2bf(float f) {   // round-to-nearest-even
  u32 x = __builtin_bit_cast(u32, f);
  x += 0x7fffu + ((x >> 16) & 1u);
  return (u16)(x >> 16);
}

// ---------------- Kernel 0: train_mask encoding detector ----------------
// int32 mask (0/1) -> every u32 word is 0 or 1. byte-bool mask -> words pack
// 4 bools, so some word has a byte set above bit 1 (random 50% mask => certain).
__global__ __launch_bounds__(256) void k_detect(const u32* __restrict__ tm, int* __restrict__ flag)
{
  __shared__ int s;
  if (threadIdx.x == 0) s = 0;
  __syncthreads();
  int local = 0;
  for (int i = threadIdx.x; i < N_NODES / 4; i += 256) {
    if (tm[i] > 1u) local = 1;
  }
  if (local) s = 1;             // benign race: all writers store 1
  __syncthreads();
  if (threadIdx.x == 0) *flag = s;
}

// ---------------- Kernel 1: [h|xe] = relu(x @ [fc1_w;xenc_w]^T + b) ----------------
// BM=128 rows x BN=320 cols per block (single col pass: x read once).
// 512 threads = 8 waves (2 row x 4 col); each wave 64x80 = 4x5 MFMA frags.
// f32 global loads -> reg -> bf16 cvt -> LDS (LDX=40 pad: 80B row stride,
// bank-quad = row*5 mod 8 is bijective -> balanced ds_read_b128).
#define BM  128
#define BN  320
#define LDX 40

__device__ __forceinline__ void stage_load(
    int tid, int kc, long rowbase,
    const float* __restrict__ x, const float* __restrict__ fc1w, const float* __restrict__ xencw,
    f32x4 st[7])
{
  #pragma unroll
  for (int j = 0; j < 7; ++j) {
    const int g  = tid + 512 * j;            // 3584 groups: 1024 A + 2560 B
    const int k0 = kc * 32 + (g & 7) * 4;
    const bool kval = (k0 + 4 <= F_DIM);     // F%4==0: float4 fully valid or fully OOB
    f32x4 v = (f32x4){0.f, 0.f, 0.f, 0.f};
    if (g < 1024) {
      const long rr = rowbase + (g >> 3);
      if (kval && rr < N_NODES) v = *(const f32x4*)(x + rr * F_DIM + k0);
    } else {
      const int o = (g - 1024) >> 3;
      if (kval) {
        const float* p = (o < H_DIM) ? (fc1w + (long)o * F_DIM + k0)
                                     : (xencw + (long)(o - H_DIM) * F_DIM + k0);
        v = *(const f32x4*)p;
      }
    }
    st[j] = v;
  }
}

__device__ __forceinline__ void stage_store(int tid, u16* __restrict__ sA, u16* __restrict__ sB,
                                            const f32x4 st[7])
{
  #pragma unroll
  for (int j = 0; j < 7; ++j) {
    const int g = tid + 512 * j;
    u16x4 b;
    #pragma unroll
    for (int i = 0; i < 4; ++i) b[i] = f2bf(st[j][i]);
    u16* dst;
    if (g < 1024) dst = sA + (g >> 3) * LDX + (g & 7) * 4;
    else          dst = sB + ((g - 1024) >> 3) * LDX + (g & 7) * 4;
    *(u16x4*)dst = b;   // 8B aligned: row*80 + (g&7)*8
  }
}

__global__ __launch_bounds__(512) void k_gemm1(
    const float* __restrict__ x, const float* __restrict__ fc1w, const float* __restrict__ fc1b,
    const float* __restrict__ xencw, const float* __restrict__ xencb, u16* __restrict__ hout)
{
  __shared__ u16 sA[2][BM * LDX];   // 2 * 10240 B
  __shared__ u16 sB[2][BN * LDX];   // 2 * 25600 B   (71680 B total -> 2 blocks/CU)
  const int tid  = threadIdx.x;
  const int lane = tid & 63;
  const int wid  = tid >> 6;
  const int wr = wid >> 2, wc = wid & 3;
  const long rowbase = (long)blockIdx.x * BM;

  f32x4 acc[4][5];
  #pragma unroll
  for (int m = 0; m < 4; ++m)
    #pragma unroll
    for (int n = 0; n < 5; ++n)
      acc[m][n] = (f32x4){0.f, 0.f, 0.f, 0.f};

  f32x4 st[7];
  stage_load(tid, 0, rowbase, x, fc1w, xencw, st);
  stage_store(tid, &sA[0][0], &sB[0][0], st);
  __syncthreads();

  for (int kc = 0; kc < 16; ++kc) {
    const int cur = kc & 1;
    if (kc < 15) stage_load(tid, kc + 1, rowbase, x, fc1w, xencw, st);

    bf16x8 a[4], b[5];
    const u16* pa = &sA[cur][(wr * 64 + (lane & 15)) * LDX + (lane >> 4) * 8];
    #pragma unroll
    for (int m = 0; m < 4; ++m) a[m] = *(const bf16x8*)(pa + m * 16 * LDX);
    const u16* pb = &sB[cur][(wc * 80 + (lane & 15)) * LDX + (lane >> 4) * 8];
    #pragma unroll
    for (int n = 0; n < 5; ++n) b[n] = *(const bf16x8*)(pb + n * 16 * LDX);

    #pragma unroll
    for (int m = 0; m < 4; ++m)
      #pragma unroll
      for (int n = 0; n < 5; ++n)
        acc[m][n] = __builtin_amdgcn_mfma_f32_16x16x32_bf16(a[m], b[n], acc[m][n], 0, 0, 0);

    if (kc < 15) stage_store(tid, &sA[cur ^ 1][0], &sB[cur ^ 1][0], st);
    __syncthreads();   // protects both: frag reads of cur done; writes to cur^1 visible
  }

  // epilogue: bias + relu + bf16 store. C/D: col=lane&15, row=(lane>>4)*4+reg.
  #pragma unroll
  for (int n = 0; n < 5; ++n) {
    const int col = wc * 80 + n * 16 + (lane & 15);
    const float bias = (col < H_DIM) ? fc1b[col] : xencb[col - H_DIM];
    #pragma unroll
    for (int m = 0; m < 4; ++m) {
      const long row0 = rowbase + wr * 64 + m * 16 + ((lane >> 4) << 2);
      #pragma unroll
      for (int rg = 0; rg < 4; ++rg) {
        const long rr = row0 + rg;
        if (rr < N_NODES) {
          const float v = fmaxf(acc[m][n][rg] + bias, 0.f);
          hout[rr * O_DIM + col] = f2bf(v);
        }
      }
    }
  }
}

// ---------------- Kernel 2: logits -> log_softmax -> y_prob(mask) -> s_q/s_k ----------------
// 8 lanes per row (lane = rowsub*8 + cg); each lane computes 5 of the 40 logits.
__global__ __launch_bounds__(256) void k_rowhead(
    const u16* __restrict__ hws, const int* __restrict__ y, const void* __restrict__ tmask,
    const float* __restrict__ fc2w, const float* __restrict__ fc2b, const float* __restrict__ pw,
    const int* __restrict__ mask_flag,
    float* __restrict__ out_lp, float* __restrict__ sq_out, float* __restrict__ sk_out)
{
  const int tid = threadIdx.x;
  const int lane = tid & 63, wid = tid >> 6;
  const int rowsub = lane >> 3, cg = lane & 7;
  const long row = (long)blockIdx.x * 32 + wid * 8 + rowsub;
  if (row >= N_NODES) return;
  const u16* hrow = hws + row * O_DIM;

  float lg[5];
  #pragma unroll
  for (int i = 0; i < 5; ++i) lg[i] = fc2b[cg * 5 + i];

  for (int h0 = 0; h0 < H_DIM; h0 += 8) {
    const u16x8 hv = *(const u16x8*)(hrow + h0);
    float hf[8];
    #pragma unroll
    for (int i = 0; i < 8; ++i) hf[i] = bf2f(hv[i]);
    #pragma unroll
    for (int i = 0; i < 5; ++i) {
      const float* wv = fc2w + (cg * 5 + i) * H_DIM + h0;
      const f32x4 w0 = *(const f32x4*)wv;
      const f32x4 w1 = *(const f32x4*)(wv + 4);
      #pragma unroll
      for (int k = 0; k < 4; ++k) lg[i] += hf[k] * w0[k];
      #pragma unroll
      for (int k = 0; k < 4; ++k) lg[i] += hf[4 + k] * w1[k];
    }
  }

  float m = lg[0];
  #pragma unroll
  for (int i = 1; i < 5; ++i) m = fmaxf(m, lg[i]);
  #pragma unroll
  for (int off = 1; off < 8; off <<= 1) m = fmaxf(m, __shfl_xor(m, off));
  float ex[5], s = 0.f;
  #pragma unroll
  for (int i = 0; i < 5; ++i) { ex[i] = __expf(lg[i] - m); s += ex[i]; }
  #pragma unroll
  for (int off = 1; off < 8; off <<= 1) s += __shfl_xor(s, off);
  const float lse = m + __logf(s);
  const float inv = 1.f / s;

  const int yv = y[row];
  const bool byte_mask = (*mask_flag != 0);
  const bool tm = byte_mask ? (((const unsigned char*)tmask)[row] != 0)
                            : (((const int*)tmask)[row] != 0);
  float sq = 0.f, sk = 0.f;
  #pragma unroll
  for (int i = 0; i < 5; ++i) {
    const int c = cg * 5 + i;
    out_lp[row * C_DIM + c] = lg[i] - lse;
    const float p = tm ? (c == yv ? 1.f : 0.f) : ex[i] * inv;
    sq += p * pw[2 * HX_DIM + c];            // w_yq
    sk += p * pw[2 * HX_DIM + C_DIM + c];    // w_yk
  }
  // xe contribution: this lane covers xe[cg*8 .. cg*8+8)
  const u16x8 xv = *(const u16x8*)(hrow + H_DIM + cg * 8);
  #pragma unroll
  for (int i = 0; i < 8; ++i) {
    const float xe = bf2f(xv[i]);
    sq += xe * pw[cg * 8 + i];               // w_xq
    sk += xe * pw[HX_DIM + cg * 8 + i];      // w_xk
  }
  #pragma unroll
  for (int off = 1; off < 8; off <<= 1) {
    sq += __shfl_xor(sq, off);
    sk += __shfl_xor(sk, off);
  }
  if (cg == 0) { sq_out[row] = sq; sk_out[row] = sk; }
}

// ---------------- Kernel 3: edge scores ----------------
__global__ __launch_bounds__(256) void k_edges(
    const int* __restrict__ ei, const int* __restrict__ ein,
    const float* __restrict__ sq, const float* __restrict__ sk,
    const float* __restrict__ pb, float* __restrict__ out)
{
  const int e = blockIdx.x * 256 + threadIdx.x;
  if (e >= E_NUM) return;
  const float b = pb[0];
  const int a0 = ei[e],  a1 = ei[E_NUM + e];
  out[e] = sq[a0] + sk[a1] + b;
  const int c0 = ein[e], c1 = ein[E_NUM + e];
  out[E_NUM + e] = sq[c0] + sk[c1] + b;
}

extern "C" void kernel_launch(void* const* d_in, const int* in_sizes, int n_in,
                              void* d_out, int out_size, void* d_ws, size_t ws_size,
                              hipStream_t stream)
{
  const float* x     = (const float*)d_in[0];
  const int*   y     = (const int*)d_in[1];
  const void*  tm    = d_in[2];
  const int*   ei    = (const int*)d_in[3];
  const int*   ein   = (const int*)d_in[4];
  const float* fc1w  = (const float*)d_in[5];
  const float* fc1b  = (const float*)d_in[6];
  const float* fc2w  = (const float*)d_in[7];
  const float* fc2b  = (const float*)d_in[8];
  const float* xencw = (const float*)d_in[9];
  const float* xencb = (const float*)d_in[10];
  const float* pw    = (const float*)d_in[11];
  const float* pb    = (const float*)d_in[12];
  float* out = (float*)d_out;

  // workspace layout: h|xe (N x 320 bf16, 64 MB) | s_q (N f32) | s_k (N f32) | flag (int)
  u16*   hws  = (u16*)d_ws;
  float* sq   = (float*)((char*)d_ws + (size_t)N_NODES * O_DIM * 2);
  float* sk   = sq + N_NODES;
  int*   flag = (int*)(sk + N_NODES);

  k_detect <<<1, 256, 0, stream>>>((const u32*)tm, flag);
  const int nrb = (N_NODES + BM - 1) / BM;   // 782
  k_gemm1  <<<nrb, 512, 0, stream>>>(x, fc1w, fc1b, xencw, xencb, hws);
  k_rowhead<<<(N_NODES + 31) / 32, 256, 0, stream>>>(hws, y, tm, fc2w, fc2b, pw, flag,
                                                     out + 2 * (size_t)E_NUM, sq, sk);
  k_edges  <<<E_NUM / 256, 256, 0, stream>>>(ei, ein, sq, sk, pb, out);
}